// Round 21
// baseline (277.253 us; speedup 1.0000x reference)
//
#include <hip/hip_runtime.h>
#include <stdint.h>
#include <stddef.h>

#define L_SEQ 2048
#define NB 4
#define NH 16
#define HDIM 64
#define DMODEL 1024
// 1/sqrt(64) * log2(e): softmax computed in exp2 domain
#define ATT_SCALE_L2E 0.1803368801f

typedef __attribute__((ext_vector_type(4))) float f32x4;
typedef __attribute__((ext_vector_type(16))) float f32x16;
typedef __attribute__((ext_vector_type(8))) __bf16 bf16x8;
typedef __attribute__((ext_vector_type(4))) __bf16 bf16x4;

__device__ __forceinline__ void gload16(const void* g, void* l) {
  __builtin_amdgcn_global_load_lds((const __attribute__((address_space(1))) void*)g,
                                   (__attribute__((address_space(3))) void*)l, 16, 0, 0);
}

// ---------------- fused prep: convert x + transpose both weights ----------------
// grid 12288 x 256thr: [0,8192) convert_x; [8192,11264) Wqkv^T; [11264,12288) Wout^T
__global__ void k_prep(const float* __restrict__ x, __bf16* __restrict__ xb,
                       const float* __restrict__ Wqkv, __bf16* __restrict__ Wqkvt,
                       const float* __restrict__ Wout, __bf16* __restrict__ Woutt) {
  __shared__ float t[32][33];
  const int bid = blockIdx.x, tid = threadIdx.x;
  if (bid < 8192) {
    int i = (bid * 256 + tid) * 4;
    float4 v = *(const float4*)(x + i);
    bf16x4 o;
    o[0] = (__bf16)v.x; o[1] = (__bf16)v.y; o[2] = (__bf16)v.z; o[3] = (__bf16)v.w;
    *(bf16x4*)(xb + i) = o;
    return;
  }
  const float* W; __bf16* Wt; int R, C, bx, by;
  if (bid < 11264) {
    W = Wqkv; Wt = Wqkvt; R = 1024; C = 3072;
    bx = (bid - 8192) % 96; by = (bid - 8192) / 96;
  } else {
    W = Wout; Wt = Woutt; R = 1024; C = 1024;
    bx = (bid - 11264) % 32; by = (bid - 11264) / 32;
  }
  int c0 = bx * 32, r0 = by * 32;
  int tx = tid & 31, ty = tid >> 5;  // 32 x 8
#pragma unroll
  for (int i = 0; i < 32; i += 8)
    t[ty + i][tx] = W[(size_t)(r0 + ty + i) * C + c0 + tx];
  __syncthreads();
#pragma unroll
  for (int i = 0; i < 32; i += 8)
    Wt[(size_t)(c0 + ty + i) * R + r0 + tx] = (__bf16)t[tx][ty + i];
}

// ------- m97-structure GEMM + T2 swizzle + 3-buffer depth-2 (round-15 best) ----
// Plain 2D raster grid (A/B vs XCD-sliced decode: raster wins, rounds 15/19).
template <int EPI>
__global__ __launch_bounds__(256, 3) void k_gemm(
    const __bf16* __restrict__ A, const __bf16* __restrict__ Bt,
    const float* __restrict__ bias, float* __restrict__ Cf,
    __bf16* __restrict__ Qo, __bf16* __restrict__ Ko, __bf16* __restrict__ Vto,
    int M, int N, int K) {
  __shared__ __align__(16) char lds[3 * 16384];  // buf = As 8KB + Bs 8KB
  const int tid = threadIdx.x;
  const int wave = tid >> 6, lane = tid & 63;
  const int brow = blockIdx.y * 128, bcol = blockIdx.x * 128;
  const int wr = wave >> 1, wc = wave & 1;
  const int g = lane >> 4, c16 = lane & 15;
  const int fx = ((c16 >> 1) & 3) << 4;   // ds_read byte-XOR (T2)

  f32x4 acc[4][4] = {};

  const int scol = ((tid & 3) * 8) ^ (((tid >> 3) & 3) << 3);
  const __bf16* aSrc = A + (size_t)(brow + (tid >> 2)) * K + scol;
  const __bf16* bSrc = Bt + (size_t)(bcol + (tid >> 2)) * K + scol;
  const int NT = K >> 5;

#define STAGE(kt, sel) do {                                                   \
    char* lb_ = lds + (sel) * 16384 + wave * 1024;                            \
    gload16(aSrc + (kt) * 32, lb_);                                           \
    gload16(aSrc + (size_t)64 * K + (kt) * 32, lb_ + 4096);                   \
    gload16(bSrc + (kt) * 32, lb_ + 8192);                                    \
    gload16(bSrc + (size_t)64 * K + (kt) * 32, lb_ + 8192 + 4096);            \
  } while (0)

  STAGE(0, 0);
  STAGE(1, 1);
  asm volatile("s_waitcnt vmcnt(4)" ::: "memory");  // tile 0 landed
  asm volatile("s_barrier" ::: "memory");

  int bs = 0;  // buffer of current tile
  for (int kt = 0; kt < NT; ++kt) {
    if (kt < NT - 2) {
      int sel = (bs == 0) ? 2 : bs - 1;  // (bs+2)%3: consumed at kt-1, safe
      STAGE(kt + 2, sel);
    }
    const char* bufA = lds + bs * 16384;
    const char* bufB = bufA + 8192;
    bf16x8 af[4], bfr[4];
#pragma unroll
    for (int m = 0; m < 4; ++m) {
      int rr = wr * 64 + m * 16 + c16;
      af[m] = *(const bf16x8*)(bufA + rr * 64 + ((g * 16) ^ fx));
    }
#pragma unroll
    for (int n = 0; n < 4; ++n) {
      int rr = wc * 64 + n * 16 + c16;
      bfr[n] = *(const bf16x8*)(bufB + rr * 64 + ((g * 16) ^ fx));
    }
#pragma unroll
    for (int m = 0; m < 4; ++m)
#pragma unroll
      for (int n = 0; n < 4; ++n)
        acc[m][n] = __builtin_amdgcn_mfma_f32_16x16x32_bf16(af[m], bfr[n], acc[m][n], 0, 0, 0);
    if (kt < NT - 2)
      asm volatile("s_waitcnt vmcnt(4)" ::: "memory");  // tile kt+1 landed
    else if (kt == NT - 2)
      asm volatile("s_waitcnt vmcnt(0)" ::: "memory");
    if (kt < NT - 1) asm volatile("s_barrier" ::: "memory");
    bs = (bs == 2) ? 0 : bs + 1;
  }
#undef STAGE

#pragma unroll
  for (int m = 0; m < 4; ++m) {
#pragma unroll
    for (int n = 0; n < 4; ++n) {
      int gcol = bcol + wc * 64 + n * 16 + c16;
      float bv = bias[gcol];
#pragma unroll
      for (int r = 0; r < 4; ++r) {
        int grow = brow + wr * 64 + m * 16 + g * 4 + r;
        float v = acc[m][n][r] + bv;
        if (EPI == 0) {
          int which = gcol >> 10, hh = (gcol >> 6) & 15, d = gcol & 63;
          int b = grow >> 11, l = grow & 2047;
          size_t bh = (size_t)b * NH + hh;
          if (which == 0)
            Qo[(bh * L_SEQ + l) * HDIM + d] = (__bf16)(v * ATT_SCALE_L2E);
          else if (which == 1)
            Ko[(bh * L_SEQ + l) * HDIM + d] = (__bf16)v;
          else
            Vto[(bh * HDIM + d) * L_SEQ + l] = (__bf16)v;
        } else {
          Cf[(size_t)grow * N + gcol] = v;
        }
      }
    }
  }
}

// ---------------- helpers ----------------
__device__ __forceinline__ float fexp2(float x) {
  float r;
  asm("v_exp_f32 %0, %1" : "=v"(r) : "v"(x));
  return r;
}
// exp path: MUST keep a compiler-visible VALU op (the -4.0f sub) between the
// MFMA result and v_exp_f32 (rounds 12/18 failed without it; 13/15/19/20 pass).
#define EXPW(x) fexp2((x) - 4.0f)
__device__ __forceinline__ int cvtpk(float a, float b) {
  int r;
  asm("v_cvt_pk_bf16_f32 %0, %1, %2" : "=v"(r) : "v"(a), "v"(b));
  return r;
}
// only safe when a,b are DISTINCT values (distinct registers) — round-4 lesson
__device__ __forceinline__ void pswap(int& a, int& b) {
  asm("v_permlane32_swap_b32 %0, %1" : "+v"(a), "+v"(b));
}
// Build PV A-fragment from 8 in-lane P values (verified rounds 1-3)
__device__ __forceinline__ bf16x8 make_pa(float p0, float p1, float p2, float p3,
                                          float p4, float p5, float p6, float p7) {
  int a0 = cvtpk(p0, p1);
  int a1 = cvtpk(p2, p3);
  int b0 = cvtpk(p4, p5);
  int b1 = cvtpk(p6, p7);
  pswap(a0, b0);
  pswap(a1, b1);
  union { int i[4]; bf16x8 v; } u;
  u.i[0] = a0; u.i[1] = a1; u.i[2] = b0; u.i[3] = b1;
  return u.v;
}

// ---------------- flash attention (round-15 verified; 5 blocks/CU) ----------------
// 32KB LDS x 5 = exactly 160KB/CU; VGPR ~80 <= 512/5=102 -> no spill expected.
__global__ __launch_bounds__(256, 5) void k_attn(
    const __bf16* __restrict__ Q, const __bf16* __restrict__ K,
    const __bf16* __restrict__ Vt, __bf16* __restrict__ O) {
  __shared__ char kv_lds[32768];

  const int blk = blockIdx.x;                    // 0..1023
  const int idx = (blk & 7) * 128 + (blk >> 3);  // bijective XCD swizzle
  const int bh = idx >> 4;
  const int qt = idx & 15;
  const int tid = threadIdx.x;
  const int wave = tid >> 6, lane = tid & 63;
  const int r31 = lane & 31, hi = lane >> 5;
  const int swz = (r31 & 7) << 4;
  const int qw = qt * 128 + wave * 32;
  const __bf16* Qb = Q + (size_t)bh * L_SEQ * HDIM;
  const char* Kc = (const char*)(K + (size_t)bh * L_SEQ * HDIM);
  const char* Vc = (const char*)(Vt + (size_t)bh * HDIM * L_SEQ);

  const char* gK0; const char* gK1; const char* gV0; const char* gV1;
  {
    int Y0 = tid * 16, Y1 = 4096 + tid * 16;
    int r0 = Y0 >> 7, r1 = Y1 >> 7;
    int c0 = (Y0 & 127) ^ ((r0 & 7) << 4);
    int c1 = (Y1 & 127) ^ ((r1 & 7) << 4);
    gK0 = Kc + r0 * 128 + c0;
    gK1 = Kc + r1 * 128 + c1;
    gV0 = Vc + (size_t)r0 * 4096 + c0;
    gV1 = Vc + (size_t)r1 * 4096 + c1;
  }

  bf16x8 qf[4];
#pragma unroll
  for (int kc = 0; kc < 4; ++kc)
    qf[kc] = *(const bf16x8*)(Qb + (size_t)(qw + r31) * HDIM + kc * 16 + hi * 8);

  bf16x8 vones;
#pragma unroll
  for (int i = 0; i < 8; ++i) vones[i] = (__bf16)1.0f;

  f32x16 o0 = {}, o1 = {}, la = {};

#define STAGEA(buf, kvb) do {                                                    \
    char* lb_ = kv_lds + (buf) * 16384 + wave * 1024;                            \
    gload16(gK0 + (size_t)(kvb) * 128, lb_);                                     \
    gload16(gK1 + (size_t)(kvb) * 128, lb_ + 4096);                              \
    gload16(gV0 + (kvb) * 2, lb_ + 8192);                                        \
    gload16(gV1 + (kvb) * 2, lb_ + 8192 + 4096);                                 \
  } while (0)

#define BODYL(t, bufo) do {                                                        \
    const char* kb_ = kv_lds + (bufo) + ((t) * 32 + r31) * 128;                    \
    bf16x8 kf0 = *(const bf16x8*)(kb_ + ((hi * 16) ^ swz));                        \
    bf16x8 kf1 = *(const bf16x8*)(kb_ + ((32 + hi * 16) ^ swz));                   \
    bf16x8 kf2 = *(const bf16x8*)(kb_ + ((64 + hi * 16) ^ swz));                   \
    bf16x8 kf3 = *(const bf16x8*)(kb_ + ((96 + hi * 16) ^ swz));                   \
    f32x16 s = {};                                                                 \
    s = __builtin_amdgcn_mfma_f32_32x32x16_bf16(kf0, qf[0], s, 0, 0, 0);           \
    s = __builtin_amdgcn_mfma_f32_32x32x16_bf16(kf1, qf[1], s, 0, 0, 0);           \
    s = __builtin_amdgcn_mfma_f32_32x32x16_bf16(kf2, qf[2], s, 0, 0, 0);           \
    s = __builtin_amdgcn_mfma_f32_32x32x16_bf16(kf3, qf[3], s, 0, 0, 0);           \
    _Pragma("unroll") for (int i = 0; i < 16; ++i) s[i] = EXPW(s[i]);              \
    const char* vb_ = kv_lds + (bufo) + 8192 + r31 * 128;                          \
    bf16x8 pa = make_pa(s[0], s[1], s[2], s[3], s[4], s[5], s[6], s[7]);           \
    o0 = __builtin_amdgcn_mfma_f32_32x32x16_bf16(                                  \
        pa, *(const bf16x8*)(vb_ + (((t) * 64 + hi * 16) ^ swz)), o0, 0, 0, 0);    \
    o1 = __builtin_amdgcn_mfma_f32_32x32x16_bf16(                                  \
        pa, *(const bf16x8*)(vb_ + 4096 + (((t) * 64 + hi * 16) ^ swz)), o1, 0, 0, 0); \
    la = __builtin_amdgcn_mfma_f32_32x32x16_bf16(pa, vones, la, 0, 0, 0);          \
    pa = make_pa(s[8], s[9], s[10], s[11], s[12], s[13], s[14], s[15]);            \
    o0 = __builtin_amdgcn_mfma_f32_32x32x16_bf16(                                  \
        pa, *(const bf16x8*)(vb_ + (((t) * 64 + 32 + hi * 16) ^ swz)), o0, 0, 0, 0); \
    o1 = __builtin_amdgcn_mfma_f32_32x32x16_bf16(                                  \
        pa, *(const bf16x8*)(vb_ + 4096 + (((t) * 64 + 32 + hi * 16) ^ swz)), o1, 0, 0, 0); \
    la = __builtin_amdgcn_mfma_f32_32x32x16_bf16(pa, vones, la, 0, 0, 0);          \
  } while (0)

  int cur = 0;
  STAGEA(0, 0);
  __syncthreads();
  for (int t = 0; t < L_SEQ / 64; ++t) {
    if (t < L_SEQ / 64 - 1) STAGEA(cur ^ 1, (t + 1) * 64);
    BODYL(0, cur * 16384);
    BODYL(1, cur * 16384);
    __syncthreads();
    cur ^= 1;
  }
#undef STAGEA
#undef BODYL

  // la[r] is the softmax denominator for the same row as o0[r]/o1[r]
  const int b = bh >> 4, h = bh & 15;
#pragma unroll
  for (int r = 0; r < 16; ++r) {
    int ql = (r & 3) + 8 * (r >> 2) + 4 * hi;
    float li = 1.f / la[r];
    size_t base = ((size_t)b * L_SEQ + qw + ql) * DMODEL + h * 64 + r31;
    O[base] = (__bf16)(o0[r] * li);
    O[base + 32] = (__bf16)(o1[r] * li);
  }
}

extern "C" void kernel_launch(void* const* d_in, const int* in_sizes, int n_in,
                              void* d_out, int out_size, void* d_ws, size_t ws_size,
                              hipStream_t stream) {
  const float* x = (const float*)d_in[0];
  const float* Wqkv = (const float*)d_in[1];
  const float* bqkv = (const float*)d_in[2];
  const float* Wout = (const float*)d_in[3];
  const float* bout = (const float*)d_in[4];
  float* out = (float*)d_out;

  char* ws = (char*)d_ws;
  __bf16* Xb    = (__bf16*)(ws + 0);
  __bf16* Wqkvt = (__bf16*)(ws + 16777216);
  __bf16* Woutt = (__bf16*)(ws + 23068672);
  __bf16* Qb    = (__bf16*)(ws + 25165824);
  __bf16* Kb    = (__bf16*)(ws + 41943040);
  __bf16* Vtb   = (__bf16*)(ws + 58720256);
  __bf16* Ob    = (__bf16*)(ws + 0);  // reuse Xb region after GEMM1

  k_prep<<<dim3(12288), 256, 0, stream>>>(x, Xb, Wqkv, Wqkvt, Wout, Woutt);
  // QKV projection: M=8192, N=3072 (128x128 tiles, 2D raster grid)
  k_gemm<0><<<dim3(24, 64), 256, 0, stream>>>(Xb, Wqkvt, bqkv, nullptr, Qb, Kb, Vtb,
                                              8192, 3072, 1024);
  k_attn<<<dim3(1024), 256, 0, stream>>>(Qb, Kb, Vtb, Ob);
  // output projection: M=8192, N=1024 (128x128 tiles, 2D raster grid)
  k_gemm<1><<<dim3(8, 64), 256, 0, stream>>>(Ob, Woutt, bout, out, nullptr, nullptr, nullptr,
                                             8192, 1024, 1024);
}

// Round 22
// 207.091 us; speedup vs baseline: 1.3388x; 1.3388x over previous
//
#include <hip/hip_runtime.h>
#include <stdint.h>
#include <stddef.h>

#define L_SEQ 2048
#define NB 4
#define NH 16
#define HDIM 64
#define DMODEL 1024
// 1/sqrt(64) * log2(e): softmax computed in exp2 domain
#define ATT_SCALE_L2E 0.1803368801f

typedef __attribute__((ext_vector_type(4))) float f32x4;
typedef __attribute__((ext_vector_type(16))) float f32x16;
typedef __attribute__((ext_vector_type(8))) __bf16 bf16x8;
typedef __attribute__((ext_vector_type(4))) __bf16 bf16x4;

__device__ __forceinline__ void gload16(const void* g, void* l) {
  __builtin_amdgcn_global_load_lds((const __attribute__((address_space(1))) void*)g,
                                   (__attribute__((address_space(3))) void*)l, 16, 0, 0);
}

// ---------------- fused prep: convert x + transpose both weights ----------------
// grid 12288 x 256thr: [0,8192) convert_x; [8192,11264) Wqkv^T; [11264,12288) Wout^T
__global__ void k_prep(const float* __restrict__ x, __bf16* __restrict__ xb,
                       const float* __restrict__ Wqkv, __bf16* __restrict__ Wqkvt,
                       const float* __restrict__ Wout, __bf16* __restrict__ Woutt) {
  __shared__ float t[32][33];
  const int bid = blockIdx.x, tid = threadIdx.x;
  if (bid < 8192) {
    int i = (bid * 256 + tid) * 4;
    float4 v = *(const float4*)(x + i);
    bf16x4 o;
    o[0] = (__bf16)v.x; o[1] = (__bf16)v.y; o[2] = (__bf16)v.z; o[3] = (__bf16)v.w;
    *(bf16x4*)(xb + i) = o;
    return;
  }
  const float* W; __bf16* Wt; int R, C, bx, by;
  if (bid < 11264) {
    W = Wqkv; Wt = Wqkvt; R = 1024; C = 3072;
    bx = (bid - 8192) % 96; by = (bid - 8192) / 96;
  } else {
    W = Wout; Wt = Woutt; R = 1024; C = 1024;
    bx = (bid - 11264) % 32; by = (bid - 11264) / 32;
  }
  int c0 = bx * 32, r0 = by * 32;
  int tx = tid & 31, ty = tid >> 5;  // 32 x 8
#pragma unroll
  for (int i = 0; i < 32; i += 8)
    t[ty + i][tx] = W[(size_t)(r0 + ty + i) * C + c0 + tx];
  __syncthreads();
#pragma unroll
  for (int i = 0; i < 32; i += 8)
    Wt[(size_t)(c0 + ty + i) * R + r0 + tx] = (__bf16)t[tx][ty + i];
}

// ------- m97-structure GEMM + T2 swizzle + 3-buffer depth-2 (round-15 best) ----
// Plain 2D raster grid (A/B vs XCD-sliced decode: raster wins, rounds 15/19).
template <int EPI>
__global__ __launch_bounds__(256, 3) void k_gemm(
    const __bf16* __restrict__ A, const __bf16* __restrict__ Bt,
    const float* __restrict__ bias, float* __restrict__ Cf,
    __bf16* __restrict__ Qo, __bf16* __restrict__ Ko, __bf16* __restrict__ Vto,
    int M, int N, int K) {
  __shared__ __align__(16) char lds[3 * 16384];  // buf = As 8KB + Bs 8KB
  const int tid = threadIdx.x;
  const int wave = tid >> 6, lane = tid & 63;
  const int brow = blockIdx.y * 128, bcol = blockIdx.x * 128;
  const int wr = wave >> 1, wc = wave & 1;
  const int g = lane >> 4, c16 = lane & 15;
  const int fx = ((c16 >> 1) & 3) << 4;   // ds_read byte-XOR (T2)

  f32x4 acc[4][4] = {};

  const int scol = ((tid & 3) * 8) ^ (((tid >> 3) & 3) << 3);
  const __bf16* aSrc = A + (size_t)(brow + (tid >> 2)) * K + scol;
  const __bf16* bSrc = Bt + (size_t)(bcol + (tid >> 2)) * K + scol;
  const int NT = K >> 5;

#define STAGE(kt, sel) do {                                                   \
    char* lb_ = lds + (sel) * 16384 + wave * 1024;                            \
    gload16(aSrc + (kt) * 32, lb_);                                           \
    gload16(aSrc + (size_t)64 * K + (kt) * 32, lb_ + 4096);                   \
    gload16(bSrc + (kt) * 32, lb_ + 8192);                                    \
    gload16(bSrc + (size_t)64 * K + (kt) * 32, lb_ + 8192 + 4096);            \
  } while (0)

  STAGE(0, 0);
  STAGE(1, 1);
  asm volatile("s_waitcnt vmcnt(4)" ::: "memory");  // tile 0 landed
  asm volatile("s_barrier" ::: "memory");

  int bs = 0;  // buffer of current tile
  for (int kt = 0; kt < NT; ++kt) {
    if (kt < NT - 2) {
      int sel = (bs == 0) ? 2 : bs - 1;  // (bs+2)%3: consumed at kt-1, safe
      STAGE(kt + 2, sel);
    }
    const char* bufA = lds + bs * 16384;
    const char* bufB = bufA + 8192;
    bf16x8 af[4], bfr[4];
#pragma unroll
    for (int m = 0; m < 4; ++m) {
      int rr = wr * 64 + m * 16 + c16;
      af[m] = *(const bf16x8*)(bufA + rr * 64 + ((g * 16) ^ fx));
    }
#pragma unroll
    for (int n = 0; n < 4; ++n) {
      int rr = wc * 64 + n * 16 + c16;
      bfr[n] = *(const bf16x8*)(bufB + rr * 64 + ((g * 16) ^ fx));
    }
#pragma unroll
    for (int m = 0; m < 4; ++m)
#pragma unroll
      for (int n = 0; n < 4; ++n)
        acc[m][n] = __builtin_amdgcn_mfma_f32_16x16x32_bf16(af[m], bfr[n], acc[m][n], 0, 0, 0);
    if (kt < NT - 2)
      asm volatile("s_waitcnt vmcnt(4)" ::: "memory");  // tile kt+1 landed
    else if (kt == NT - 2)
      asm volatile("s_waitcnt vmcnt(0)" ::: "memory");
    if (kt < NT - 1) asm volatile("s_barrier" ::: "memory");
    bs = (bs == 2) ? 0 : bs + 1;
  }
#undef STAGE

#pragma unroll
  for (int m = 0; m < 4; ++m) {
#pragma unroll
    for (int n = 0; n < 4; ++n) {
      int gcol = bcol + wc * 64 + n * 16 + c16;
      float bv = bias[gcol];
#pragma unroll
      for (int r = 0; r < 4; ++r) {
        int grow = brow + wr * 64 + m * 16 + g * 4 + r;
        float v = acc[m][n][r] + bv;
        if (EPI == 0) {
          int which = gcol >> 10, hh = (gcol >> 6) & 15, d = gcol & 63;
          int b = grow >> 11, l = grow & 2047;
          size_t bh = (size_t)b * NH + hh;
          if (which == 0)
            Qo[(bh * L_SEQ + l) * HDIM + d] = (__bf16)(v * ATT_SCALE_L2E);
          else if (which == 1)
            Ko[(bh * L_SEQ + l) * HDIM + d] = (__bf16)v;
          else
            Vto[(bh * HDIM + d) * L_SEQ + l] = (__bf16)v;
        } else {
          Cf[(size_t)grow * N + gcol] = v;
        }
      }
    }
  }
}

// ---------------- helpers ----------------
__device__ __forceinline__ float fexp2(float x) {
  float r;
  asm("v_exp_f32 %0, %1" : "=v"(r) : "v"(x));
  return r;
}
// exp path: MUST keep a compiler-visible VALU op (the -4.0f sub) between the
// MFMA result and v_exp_f32 (rounds 12/18 failed without it; 13/15/19/20 pass).
#define EXPW(x) fexp2((x) - 4.0f)
__device__ __forceinline__ int cvtpk(float a, float b) {
  int r;
  asm("v_cvt_pk_bf16_f32 %0, %1, %2" : "=v"(r) : "v"(a), "v"(b));
  return r;
}
// only safe when a,b are DISTINCT values (distinct registers) — round-4 lesson
__device__ __forceinline__ void pswap(int& a, int& b) {
  asm("v_permlane32_swap_b32 %0, %1" : "+v"(a), "+v"(b));
}
// Build PV A-fragment from 8 in-lane P values (verified rounds 1-3)
__device__ __forceinline__ bf16x8 make_pa(float p0, float p1, float p2, float p3,
                                          float p4, float p5, float p6, float p7) {
  int a0 = cvtpk(p0, p1);
  int a1 = cvtpk(p2, p3);
  int b0 = cvtpk(p4, p5);
  int b1 = cvtpk(p6, p7);
  pswap(a0, b0);
  pswap(a1, b1);
  union { int i[4]; bf16x8 v; } u;
  u.i[0] = a0; u.i[1] = a1; u.i[2] = b0; u.i[3] = b1;
  return u.v;
}

// ---------------- flash attention (round-15 verified; 4 blocks/CU max) ---------
// (256,5) spills: live set ~84 VGPR > 512/5. 4 blocks/CU is the ceiling.
__global__ __launch_bounds__(256, 4) void k_attn(
    const __bf16* __restrict__ Q, const __bf16* __restrict__ K,
    const __bf16* __restrict__ Vt, __bf16* __restrict__ O) {
  __shared__ char kv_lds[32768];

  const int blk = blockIdx.x;                    // 0..1023
  const int idx = (blk & 7) * 128 + (blk >> 3);  // bijective XCD swizzle
  const int bh = idx >> 4;
  const int qt = idx & 15;
  const int tid = threadIdx.x;
  const int wave = tid >> 6, lane = tid & 63;
  const int r31 = lane & 31, hi = lane >> 5;
  const int swz = (r31 & 7) << 4;
  const int qw = qt * 128 + wave * 32;
  const __bf16* Qb = Q + (size_t)bh * L_SEQ * HDIM;
  const char* Kc = (const char*)(K + (size_t)bh * L_SEQ * HDIM);
  const char* Vc = (const char*)(Vt + (size_t)bh * HDIM * L_SEQ);

  const char* gK0; const char* gK1; const char* gV0; const char* gV1;
  {
    int Y0 = tid * 16, Y1 = 4096 + tid * 16;
    int r0 = Y0 >> 7, r1 = Y1 >> 7;
    int c0 = (Y0 & 127) ^ ((r0 & 7) << 4);
    int c1 = (Y1 & 127) ^ ((r1 & 7) << 4);
    gK0 = Kc + r0 * 128 + c0;
    gK1 = Kc + r1 * 128 + c1;
    gV0 = Vc + (size_t)r0 * 4096 + c0;
    gV1 = Vc + (size_t)r1 * 4096 + c1;
  }

  bf16x8 qf[4];
#pragma unroll
  for (int kc = 0; kc < 4; ++kc)
    qf[kc] = *(const bf16x8*)(Qb + (size_t)(qw + r31) * HDIM + kc * 16 + hi * 8);

  bf16x8 vones;
#pragma unroll
  for (int i = 0; i < 8; ++i) vones[i] = (__bf16)1.0f;

  f32x16 o0 = {}, o1 = {}, la = {};

#define STAGEA(buf, kvb) do {                                                    \
    char* lb_ = kv_lds + (buf) * 16384 + wave * 1024;                            \
    gload16(gK0 + (size_t)(kvb) * 128, lb_);                                     \
    gload16(gK1 + (size_t)(kvb) * 128, lb_ + 4096);                              \
    gload16(gV0 + (kvb) * 2, lb_ + 8192);                                        \
    gload16(gV1 + (kvb) * 2, lb_ + 8192 + 4096);                                 \
  } while (0)

#define BODYL(t, bufo) do {                                                        \
    const char* kb_ = kv_lds + (bufo) + ((t) * 32 + r31) * 128;                    \
    bf16x8 kf0 = *(const bf16x8*)(kb_ + ((hi * 16) ^ swz));                        \
    bf16x8 kf1 = *(const bf16x8*)(kb_ + ((32 + hi * 16) ^ swz));                   \
    bf16x8 kf2 = *(const bf16x8*)(kb_ + ((64 + hi * 16) ^ swz));                   \
    bf16x8 kf3 = *(const bf16x8*)(kb_ + ((96 + hi * 16) ^ swz));                   \
    f32x16 s = {};                                                                 \
    s = __builtin_amdgcn_mfma_f32_32x32x16_bf16(kf0, qf[0], s, 0, 0, 0);           \
    s = __builtin_amdgcn_mfma_f32_32x32x16_bf16(kf1, qf[1], s, 0, 0, 0);           \
    s = __builtin_amdgcn_mfma_f32_32x32x16_bf16(kf2, qf[2], s, 0, 0, 0);           \
    s = __builtin_amdgcn_mfma_f32_32x32x16_bf16(kf3, qf[3], s, 0, 0, 0);           \
    _Pragma("unroll") for (int i = 0; i < 16; ++i) s[i] = EXPW(s[i]);              \
    const char* vb_ = kv_lds + (bufo) + 8192 + r31 * 128;                          \
    bf16x8 pa = make_pa(s[0], s[1], s[2], s[3], s[4], s[5], s[6], s[7]);           \
    o0 = __builtin_amdgcn_mfma_f32_32x32x16_bf16(                                  \
        pa, *(const bf16x8*)(vb_ + (((t) * 64 + hi * 16) ^ swz)), o0, 0, 0, 0);    \
    o1 = __builtin_amdgcn_mfma_f32_32x32x16_bf16(                                  \
        pa, *(const bf16x8*)(vb_ + 4096 + (((t) * 64 + hi * 16) ^ swz)), o1, 0, 0, 0); \
    la = __builtin_amdgcn_mfma_f32_32x32x16_bf16(pa, vones, la, 0, 0, 0);          \
    pa = make_pa(s[8], s[9], s[10], s[11], s[12], s[13], s[14], s[15]);            \
    o0 = __builtin_amdgcn_mfma_f32_32x32x16_bf16(                                  \
        pa, *(const bf16x8*)(vb_ + (((t) * 64 + 32 + hi * 16) ^ swz)), o0, 0, 0, 0); \
    o1 = __builtin_amdgcn_mfma_f32_32x32x16_bf16(                                  \
        pa, *(const bf16x8*)(vb_ + 4096 + (((t) * 64 + 32 + hi * 16) ^ swz)), o1, 0, 0, 0); \
    la = __builtin_amdgcn_mfma_f32_32x32x16_bf16(pa, vones, la, 0, 0, 0);          \
  } while (0)

  int cur = 0;
  STAGEA(0, 0);
  __syncthreads();
  for (int t = 0; t < L_SEQ / 64; ++t) {
    if (t < L_SEQ / 64 - 1) STAGEA(cur ^ 1, (t + 1) * 64);
    BODYL(0, cur * 16384);
    BODYL(1, cur * 16384);
    __syncthreads();
    cur ^= 1;
  }
#undef STAGEA
#undef BODYL

  // la[r] is the softmax denominator for the same row as o0[r]/o1[r]
  const int b = bh >> 4, h = bh & 15;
#pragma unroll
  for (int r = 0; r < 16; ++r) {
    int ql = (r & 3) + 8 * (r >> 2) + 4 * hi;
    float li = 1.f / la[r];
    size_t base = ((size_t)b * L_SEQ + qw + ql) * DMODEL + h * 64 + r31;
    O[base] = (__bf16)(o0[r] * li);
    O[base + 32] = (__bf16)(o1[r] * li);
  }
}

extern "C" void kernel_launch(void* const* d_in, const int* in_sizes, int n_in,
                              void* d_out, int out_size, void* d_ws, size_t ws_size,
                              hipStream_t stream) {
  const float* x = (const float*)d_in[0];
  const float* Wqkv = (const float*)d_in[1];
  const float* bqkv = (const float*)d_in[2];
  const float* Wout = (const float*)d_in[3];
  const float* bout = (const float*)d_in[4];
  float* out = (float*)d_out;

  char* ws = (char*)d_ws;
  __bf16* Xb    = (__bf16*)(ws + 0);
  __bf16* Wqkvt = (__bf16*)(ws + 16777216);
  __bf16* Woutt = (__bf16*)(ws + 23068672);
  __bf16* Qb    = (__bf16*)(ws + 25165824);
  __bf16* Kb    = (__bf16*)(ws + 41943040);
  __bf16* Vtb   = (__bf16*)(ws + 58720256);
  __bf16* Ob    = (__bf16*)(ws + 0);  // reuse Xb region after GEMM1

  k_prep<<<dim3(12288), 256, 0, stream>>>(x, Xb, Wqkv, Wqkvt, Wout, Woutt);
  // QKV projection: M=8192, N=3072 (128x128 tiles, 2D raster grid)
  k_gemm<0><<<dim3(24, 64), 256, 0, stream>>>(Xb, Wqkvt, bqkv, nullptr, Qb, Kb, Vtb,
                                              8192, 3072, 1024);
  k_attn<<<dim3(1024), 256, 0, stream>>>(Qb, Kb, Vtb, Ob);
  // output projection: M=8192, N=1024 (128x128 tiles, 2D raster grid)
  k_gemm<1><<<dim3(8, 64), 256, 0, stream>>>(Ob, Woutt, bout, out, nullptr, nullptr, nullptr,
                                             8192, 1024, 1024);
}